// Round 8
// baseline (219.634 us; speedup 1.0000x reference)
//
#include <hip/hip_runtime.h>

// SpanRepresentation R7: canonical grid-stride streaming copy (fill-like).
// Single variable change vs R3: NO nontemporal stores, NO manual unroll.
// vs R5: canonical whole-grid sweep instead of per-block windows.
// out flat = 12,659,616 float4; per-element branchless source decode.

typedef float f4 __attribute__((ext_vector_type(4)));

#define TOTAL4  12659616   // 8*4068*389 float4 = 202.6 MB

__global__ __launch_bounds__(256) void span_rep_stream(
    const f4* __restrict__ x,
    const f4* __restrict__ we,
    f4* __restrict__ out)
{
    const int stride = (int)gridDim.x * 256;
    for (int idx = (int)blockIdx.x * 256 + (int)threadIdx.x;
         idx < TOTAL4; idx += stride) {

        // decode output position
        const unsigned row = (unsigned)idx / 389u;     // magic mul
        const int col = idx - (int)(row * 389u);       // 0..388
        const unsigned b = row / 4068u;                // 0..7
        const int s = (int)row - (int)(b * 4068u);     // span index 0..4067

        // width-group decode: cumulative starts {0,512,1023,1533,2042,2550,3057,3563}
        int w = 1, cw = 0;
        if (s >= 512)  { w = 2; cw = 512;  }
        if (s >= 1023) { w = 3; cw = 1023; }
        if (s >= 1533) { w = 4; cw = 1533; }
        if (s >= 2042) { w = 5; cw = 2042; }
        if (s >= 2550) { w = 6; cw = 2550; }
        if (s >= 3057) { w = 7; cw = 3057; }
        if (s >= 3563) { w = 8; cw = 3563; }
        const int start = s - cw;

        // branchless source select
        const int r = (col < 192) ? start : (start + w - 1);
        const int c = (col < 192) ? col : (col - 192);
        const int xoff = ((int)b * 512 + r) * 192 + c;
        const int bucket = (int)((0x765543210ull >> (4 * w)) & 0xF);
        const int woff = bucket * 5 + (col - 384);
        const f4* src = (col < 384) ? (x + xoff) : (we + woff);

        out[idx] = *src;
    }
}

extern "C" void kernel_launch(void* const* d_in, const int* in_sizes, int n_in,
                              void* d_out, int out_size, void* d_ws, size_t ws_size,
                              hipStream_t stream) {
    const f4* x  = (const f4*)d_in[0];  // (8, 512, 768) f32
    const f4* we = (const f4*)d_in[1];  // (14, 20) f32
    f4* out = (f4*)d_out;               // (8, 4068, 1556) f32 flat

    // 2048 blocks = 8 blocks/CU, grid-stride (Guideline 11 memory-bound shape)
    span_rep_stream<<<2048, 256, 0, stream>>>(x, we, out);
}

// Round 12
// 210.134 us; speedup vs baseline: 1.0452x; 1.0452x over previous
//
#include <hip/hip_runtime.h>

// SpanRepresentation R8 (4th submit; prior three hit broker timeouts): LDS-decoupled
// pure-store stream.
// Theory: loads+stores share vmcnt on CDNA; interleaved load->store forces
// store-pipe drains on every load-wait (~1/3 fill BW). Fix: stage sources in
// LDS (phase 1), then phase 2 issues ONLY global stores (ds_read sources use
// lgkmcnt) -> store pipeline as deep as the 6.6 TB/s fill kernel.
//
// Block (r,b): x row x[b,r] appears in out exactly 16x:
//   start-role w=1..8: out[b, cw[w-1]+r,       0:768]   valid iff r+w <= 512
//   end-role   w=1..8: out[b, cw[w-1]+r-w+1, 768:1536]  valid iff r >= w-1
// plus wemb tail for the 8 spans STARTING at r (covers each span once).

typedef float f4 __attribute__((ext_vector_type(4)));

#define L_DIM 512
#define S_TOT 4068
#define ROW4  389
#define D4    192

// cw[w-1] = {0,512,1023,1533,2042,2550,3057,3563}, packed 4x16b per u64
#define CW_LO ((1533ull << 48) | (1023ull << 32) | (512ull << 16) | 0ull)
#define CW_HI ((3563ull << 48) | (3057ull << 32) | (2550ull << 16) | 2042ull)
__device__ __forceinline__ int cw_of(int k) {  // k = w-1, 0..7
    return (int)(((k < 4 ? CW_LO : CW_HI) >> (16 * (k & 3))) & 0xFFFF);
}

__global__ __launch_bounds__(256) void span_rep_lds(
    const f4* __restrict__ x,
    const f4* __restrict__ we,
    f4* __restrict__ out)
{
    __shared__ f4 lx[D4];   // the x row (3 KB)
    __shared__ f4 lw[40];   // wemb rows for w=1..8 (5 f4 each)

    const int r = blockIdx.x;
    const int b = blockIdx.y;
    const int t = (int)threadIdx.x;

    // ---- phase 1: stage (the only global loads in the kernel) ----
    if (t < D4) {
        lx[t] = x[((size_t)b * L_DIM + r) * D4 + t];
    } else if (t < D4 + 40) {
        const int u = t - D4;              // 0..39
        const int w = u / 5 + 1;           // 1..8
        const int col = u - (w - 1) * 5;   // 0..4
        const int bucket = (int)((0x765543210ull >> (4 * w)) & 0xF);
        lw[u] = we[bucket * 5 + col];
    }
    __syncthreads();

    // ---- phase 2: pure store stream (no global loads, no vmcnt waits) ----
    const size_t outB = (size_t)b * S_TOT;

    #pragma unroll
    for (int i = 0; i < 12; ++i) {         // 12*256 = 3072 = 16 segs * 192
        const int u = i * 256 + t;
        const int q = (u >> 6) / 3;        // segment 0..15
        const int e = u - q * 192;         // 0..191
        const int w = (q & 7) + 1;         // width 1..8
        const int cw = cw_of(q & 7);
        if (q < 8) {                       // start-role
            if (r + w <= L_DIM)
                out[(outB + cw + r) * ROW4 + e] = lx[e];
        } else {                           // end-role
            if (r >= w - 1)
                out[(outB + cw + r - w + 1) * ROW4 + D4 + e] = lx[e];
        }
    }
    // wemb tail: 40 float4
    if (t < 40) {
        const int w = t / 5 + 1;
        const int col = t - (w - 1) * 5;
        if (r + w <= L_DIM)
            out[(outB + cw_of(w - 1) + r) * ROW4 + 2 * D4 + col] = lw[t];
    }
}

extern "C" void kernel_launch(void* const* d_in, const int* in_sizes, int n_in,
                              void* d_out, int out_size, void* d_ws, size_t ws_size,
                              hipStream_t stream) {
    const f4* x  = (const f4*)d_in[0];  // (8, 512, 768) f32
    const f4* we = (const f4*)d_in[1];  // (14, 20) f32
    f4* out = (f4*)d_out;               // (8, 4068, 1556) f32

    dim3 grid(L_DIM, 8);                // 4096 blocks, one per (r,b)
    span_rep_lds<<<grid, 256, 0, stream>>>(x, we, out);
}